// Round 12
// baseline (62.119 us; speedup 1.0000x reference)
//
#include <hip/hip_runtime.h>

// loss = BATCH - sum_b outputs[b,:].M[target[b],:], where
//   M[t,l] = 0.5 + 0.25*[l/100==t/100] + 0.125*[l/10==t/10] + 0.125*[l==t]
//
// R12 = R11's aligned-stream engine + single-kernel ticket finish.
// Engine (unchanged, proven 28.8us): wave owns 4 contiguous rows as a flat
// 1000-float4 region; 4 independent 128B-aligned streams at chunk offsets
// 0/256/512/768; per-chunk row/t recovered by wave-uniform select chain;
// dynamic loop (static unroll serializes loads - R6/R7).
// Finish: per-block plain store -> __threadfence -> ticket atomic; LAST block
// re-reads all partials in fixed index order (bit-deterministic result).
// vs R11: removes 2nd dispatch + graph gap + 1-block reducer (~3-4us).
// 1024 blocks x 512 threads (same 32 waves/CU) halves the ticket atomics.

constexpr int BATCH   = 32768;
constexpr int NCLS    = 1000;
constexpr int BLOCKS  = 1024;              // 4 blocks/CU, fully resident
constexpr int THREADS = 512;               // 8 waves; wave owns 4 contiguous rows
constexpr int WAVES   = THREADS / 64;

__device__ __forceinline__ float wchunk(const float4 v, int cc,
                                        int t0, int t1, int t2, int t3,
                                        int a0, int a1, int a2, int a3,
                                        int b0, int b1, int b2, int b3) {
    // cc = chunk index in [0,1000); row = cc/250, l0 = (cc%250)*4
    const bool hi = cc >= 500;
    const bool q1 = cc >= 250;
    const bool q3 = cc >= 750;
    const int  t  = hi ? (q3 ? t3 : t2) : (q1 ? t1 : t0);
    const int  a  = hi ? (q3 ? a3 : a2) : (q1 ? a1 : a0);
    const int  b  = hi ? (q3 ? b3 : b2) : (q1 ? b1 : b0);
    const int  r250 = hi ? (q3 ? 750 : 500) : (q1 ? 250 : 0);
    const int  l0 = (cc - r250) * 4;
    const float xs[4] = {v.x, v.y, v.z, v.w};
    float acc = 0.0f;
    #pragma unroll
    for (int j = 0; j < 4; ++j) {
        const int l = l0 + j;
        float w = 0.5f;
        if ((unsigned)(l - a) < 100u) w += 0.25f;
        if ((unsigned)(l - b) < 10u)  w += 0.125f;
        if (l == t)                   w += 0.125f;
        acc = fmaf(xs[j], w, acc);
    }
    return acc;
}

__global__ __launch_bounds__(THREADS) void hloss(
    const float* __restrict__ outputs,
    const int*   __restrict__ target,
    float*       __restrict__ partials,
    unsigned*    __restrict__ counter,
    float*       __restrict__ out)
{
    __shared__ float red[WAVES];
    __shared__ int   lastflag;
    const int lane = threadIdx.x & 63;
    const int wid  = threadIdx.x >> 6;
    const int rowbase = blockIdx.x * (4 * WAVES) + wid * 4;  // 4 contiguous rows/wave

    // fetch the wave's 4 targets (lanes 0-3), broadcast via shfl
    int tmine = 0;
    if (lane < 4) tmine = target[rowbase + lane];
    const int t0 = __shfl(tmine, 0, 64);
    const int t1 = __shfl(tmine, 1, 64);
    const int t2 = __shfl(tmine, 2, 64);
    const int t3 = __shfl(tmine, 3, 64);
    const int a0 = (t0 / 100) * 100, b0 = (t0 / 10) * 10;
    const int a1 = (t1 / 100) * 100, b1 = (t1 / 10) * 10;
    const int a2 = (t2 / 100) * 100, b2 = (t2 / 10) * 10;
    const int a3 = (t3 / 100) * 100, b3 = (t3 / 10) * 10;

    // wave's flat region: 4 rows * 250 float4 = 1000 chunks, 128 B aligned
    const float4* f4 = reinterpret_cast<const float4*>(
        outputs + (size_t)rowbase * NCLS);
    const float4 zero4 = {0.f, 0.f, 0.f, 0.f};
    float s0 = 0.f, s1 = 0.f, s2 = 0.f, s3 = 0.f;

    // dynamic loop, 4 independent aligned streams at 0/256/512/768
    for (int c = lane; c < 256; c += 64) {
        const int c1 = c + 256, c2 = c + 512, c3 = c + 768;
        const float4 v0 = f4[c];
        const float4 v1 = f4[c1];
        const float4 v2 = f4[c2];
        const float4 v3 = (c3 < 1000) ? f4[c3] : zero4;   // only tail predicate
        s0 += wchunk(v0, c,  t0,t1,t2,t3, a0,a1,a2,a3, b0,b1,b2,b3);
        s1 += wchunk(v1, c1, t0,t1,t2,t3, a0,a1,a2,a3, b0,b1,b2,b3);
        s2 += wchunk(v2, c2, t0,t1,t2,t3, a0,a1,a2,a3, b0,b1,b2,b3);
        s3 += wchunk(v3, c3, t0,t1,t2,t3, a0,a1,a2,a3, b0,b1,b2,b3); // v3=0 on tail
    }
    float win = (s0 + s1) + (s2 + s3);

    // block reduction: butterfly -> LDS -> one partial per block
    #pragma unroll
    for (int off = 32; off > 0; off >>= 1)
        win += __shfl_xor(win, off, 64);
    if (lane == 0) red[wid] = win;
    __syncthreads();

    if (threadIdx.x == 0) {
        float p = 0.0f;
        #pragma unroll
        for (int i = 0; i < WAVES; ++i) p += red[i];
        partials[blockIdx.x] = p;
        __threadfence();                               // release partial
        const unsigned old = atomicAdd(counter, 1u);   // device-scope ticket
        if (old == BLOCKS - 1) {
            __threadfence();                           // acquire others' partials
            lastflag = 1;
        } else {
            lastflag = 0;
        }
    }
    __syncthreads();

    // ---- last block reduces all partials in fixed index order ----
    if (lastflag) {
        float s = 0.0f;
        for (int i = threadIdx.x; i < BLOCKS; i += THREADS)   // 2 each, fixed order
            s += partials[i];
        #pragma unroll
        for (int off = 32; off > 0; off >>= 1)
            s += __shfl_xor(s, off, 64);
        if (lane == 0) red[wid] = s;
        __syncthreads();
        if (threadIdx.x == 0) {
            float tot = 0.0f;
            #pragma unroll
            for (int i = 0; i < WAVES; ++i) tot += red[i];
            out[0] = (float)BATCH - tot;
        }
    }
}

extern "C" void kernel_launch(void* const* d_in, const int* in_sizes, int n_in,
                              void* d_out, int out_size, void* d_ws, size_t ws_size,
                              hipStream_t stream) {
    const float* outputs = (const float*)d_in[0];
    const int*   target  = (const int*)d_in[1];
    // d_in[2]=A, d_in[3]=W — hierarchy folded analytically (see header).
    float*    out      = (float*)d_out;
    unsigned* counter  = (unsigned*)d_ws;                 // 4B ticket at offset 0
    float*    partials = (float*)((char*)d_ws + 1024);    // 1024 floats, rewritten each call

    // counter must be 0 every call (d_ws is not re-poisoned between replays);
    // partials are fully overwritten before being read.
    hipMemsetAsync(d_ws, 0, 64, stream);

    hloss<<<dim3(BLOCKS), dim3(THREADS), 0, stream>>>(
        outputs, target, partials, counter, out);
}

// Round 13
// 29.862 us; speedup vs baseline: 2.0802x; 2.0802x over previous
//
#include <hip/hip_runtime.h>

// loss = BATCH - sum_b outputs[b,:].M[target[b],:], where
//   M[t,l] = 0.5 + 0.25*[l/100==t/100] + 0.125*[l/10==t/10] + 0.125*[l==t]
//
// R13 = R11 (proven 28.8us) + per-stream row-select specialization.
// Engine: wave owns 4 contiguous rows as a flat 1000-float4 region; 4
// independent 128B-aligned streams at chunk offsets 0/256/512/768; dynamic
// loop (static unroll serializes loads - R6/R7). Each stream spans at most
// 2 rows, so row/t/a/b resolve with ONE compare + 3 selects (stream 3: row
// fixed). Two-kernel finish: plain per-block stores + tiny reducer.
// R12 lesson: single-kernel ticket finish (same-address atomic+fence from
// 1024 blocks) costs ~33us on MI355X - never fold the finisher that way.

constexpr int BATCH   = 32768;
constexpr int NCLS    = 1000;
constexpr int BLOCKS  = 2048;              // 8 blocks/CU, fully resident
constexpr int THREADS = 256;               // 4 waves; wave owns 4 contiguous rows

// chunk cc spans rows A (below bnd) and B (at/above bnd)
__device__ __forceinline__ float wchunk2(const float4 v, int cc, int bnd,
                                         int rA, int tA, int aA, int bA,
                                         int rB, int tB, int aB, int bB) {
    const bool up = cc >= bnd;
    const int  t  = up ? tB : tA;
    const int  a  = up ? aB : aA;
    const int  b  = up ? bB : bA;
    const int  r  = up ? rB : rA;
    const int  l0 = (cc - r) * 4;
    const float xs[4] = {v.x, v.y, v.z, v.w};
    float acc = 0.0f;
    #pragma unroll
    for (int j = 0; j < 4; ++j) {
        const int l = l0 + j;
        float w = 0.5f;
        if ((unsigned)(l - a) < 100u) w += 0.25f;
        if ((unsigned)(l - b) < 10u)  w += 0.125f;
        if (l == t)                   w += 0.125f;
        acc = fmaf(xs[j], w, acc);
    }
    return acc;
}

__global__ __launch_bounds__(THREADS) void hloss_part(
    const float* __restrict__ outputs,
    const int*   __restrict__ target,
    float* __restrict__ partials)
{
    __shared__ float red[4];
    const int lane = threadIdx.x & 63;
    const int wid  = threadIdx.x >> 6;
    const int rowbase = blockIdx.x * 16 + wid * 4;   // 4 contiguous rows/wave

    // fetch the wave's 4 targets (lanes 0-3), broadcast via shfl
    int tmine = 0;
    if (lane < 4) tmine = target[rowbase + lane];
    const int t0 = __shfl(tmine, 0, 64);
    const int t1 = __shfl(tmine, 1, 64);
    const int t2 = __shfl(tmine, 2, 64);
    const int t3 = __shfl(tmine, 3, 64);
    const int a0 = (t0 / 100) * 100, b0 = (t0 / 10) * 10;
    const int a1 = (t1 / 100) * 100, b1 = (t1 / 10) * 10;
    const int a2 = (t2 / 100) * 100, b2 = (t2 / 10) * 10;
    const int a3 = (t3 / 100) * 100, b3 = (t3 / 10) * 10;

    // wave's flat region: 4 rows * 250 float4 = 1000 chunks, 128 B aligned
    const float4* f4 = reinterpret_cast<const float4*>(
        outputs + (size_t)rowbase * NCLS);
    const float4 zero4 = {0.f, 0.f, 0.f, 0.f};
    float s0 = 0.f, s1 = 0.f, s2 = 0.f, s3 = 0.f;

    // dynamic loop, 4 independent aligned streams at 0/256/512/768
    // stream windows: [0,256) rows 0/1 @250; [256,512) rows 1/2 @500;
    //                 [512,768) rows 2/3 @750; [768,1000) row 3 only.
    for (int c = lane; c < 256; c += 64) {
        const int c1 = c + 256, c2 = c + 512, c3 = c + 768;
        const float4 v0 = f4[c];
        const float4 v1 = f4[c1];
        const float4 v2 = f4[c2];
        const float4 v3 = (c3 < 1000) ? f4[c3] : zero4;   // only tail predicate
        s0 += wchunk2(v0, c,  250,   0, t0, a0, b0, 250, t1, a1, b1);
        s1 += wchunk2(v1, c1, 500, 250, t1, a1, b1, 500, t2, a2, b2);
        s2 += wchunk2(v2, c2, 750, 500, t2, a2, b2, 750, t3, a3, b3);
        s3 += wchunk2(v3, c3,   0, 750, t3, a3, b3, 750, t3, a3, b3); // row 3 fixed
    }
    float win = (s0 + s1) + (s2 + s3);

    // block reduction: butterfly -> LDS -> one plain store per block
    #pragma unroll
    for (int off = 32; off > 0; off >>= 1)
        win += __shfl_xor(win, off, 64);
    if (lane == 0) red[wid] = win;
    __syncthreads();
    if (threadIdx.x == 0)
        partials[blockIdx.x] = (red[0] + red[1]) + (red[2] + red[3]);
}

__global__ __launch_bounds__(THREADS) void hloss_final(
    const float* __restrict__ partials,
    float* __restrict__ out)
{
    __shared__ float red[4];
    const int lane = threadIdx.x & 63;
    const int wid  = threadIdx.x >> 6;
    float s = 0.0f;
    for (int i = threadIdx.x; i < BLOCKS; i += THREADS)   // 8 each, fixed order
        s += partials[i];
    #pragma unroll
    for (int off = 32; off > 0; off >>= 1)
        s += __shfl_xor(s, off, 64);
    if (lane == 0) red[wid] = s;
    __syncthreads();
    if (threadIdx.x == 0)
        out[0] = (float)BATCH - ((red[0] + red[1]) + (red[2] + red[3]));
}

extern "C" void kernel_launch(void* const* d_in, const int* in_sizes, int n_in,
                              void* d_out, int out_size, void* d_ws, size_t ws_size,
                              hipStream_t stream) {
    const float* outputs = (const float*)d_in[0];
    const int*   target  = (const int*)d_in[1];
    // d_in[2]=A, d_in[3]=W — hierarchy folded analytically (see header).
    float* out      = (float*)d_out;
    float* partials = (float*)d_ws;   // 2048 floats, fully rewritten each call

    hloss_part <<<dim3(BLOCKS), dim3(THREADS), 0, stream>>>(outputs, target, partials);
    hloss_final<<<dim3(1),      dim3(THREADS), 0, stream>>>(partials, out);
}

// Round 14
// 27.698 us; speedup vs baseline: 2.2427x; 1.0781x over previous
//
#include <hip/hip_runtime.h>

// loss = BATCH - sum_b outputs[b,:].M[target[b],:], where
//   M[t,l] = 0.5 + 0.25*[l/100==t/100] + 0.125*[l/10==t/10] + 0.125*[l==t]
//
// R14 = R11's engine verbatim (best measured: 28.8us) + single-wave finisher.
// Engine: wave owns 4 contiguous rows as a flat 1000-float4 region; 4
// independent 128B-aligned streams at chunk offsets 0/256/512/768 (4000B row
// stride is 32B-misaligned, so per-row streams split cache lines; flat
// phasing fixes it); per-chunk row/t via generic select chain; dynamic loop
// (R6/R7: static full unroll serializes loads). Two-kernel finish with plain
// stores (R12: single-kernel ticket atomics cost +33us - never again).
// Finisher: one 64-lane wave, 8 float4/lane, butterfly only - no LDS/syncs.
//
// Ceiling accounting (R5..R13): 131.07MB irreducible reads at ~5.2TB/s
// effective (plateau across 5 engine variants) + ~3us finish = ~28.7us.

constexpr int BATCH   = 32768;
constexpr int NCLS    = 1000;
constexpr int BLOCKS  = 2048;              // 8 blocks/CU, fully resident
constexpr int THREADS = 256;               // 4 waves; wave owns 4 contiguous rows

__device__ __forceinline__ float wchunk(const float4 v, int cc,
                                        int t0, int t1, int t2, int t3,
                                        int a0, int a1, int a2, int a3,
                                        int b0, int b1, int b2, int b3) {
    // cc = chunk index in [0,1000); row = cc/250, l0 = (cc%250)*4
    const bool hi = cc >= 500;
    const bool q1 = cc >= 250;
    const bool q3 = cc >= 750;
    const int  t  = hi ? (q3 ? t3 : t2) : (q1 ? t1 : t0);
    const int  a  = hi ? (q3 ? a3 : a2) : (q1 ? a1 : a0);
    const int  b  = hi ? (q3 ? b3 : b2) : (q1 ? b1 : b0);
    const int  r250 = hi ? (q3 ? 750 : 500) : (q1 ? 250 : 0);
    const int  l0 = (cc - r250) * 4;
    const float xs[4] = {v.x, v.y, v.z, v.w};
    float acc = 0.0f;
    #pragma unroll
    for (int j = 0; j < 4; ++j) {
        const int l = l0 + j;
        float w = 0.5f;
        if ((unsigned)(l - a) < 100u) w += 0.25f;
        if ((unsigned)(l - b) < 10u)  w += 0.125f;
        if (l == t)                   w += 0.125f;
        acc = fmaf(xs[j], w, acc);
    }
    return acc;
}

__global__ __launch_bounds__(THREADS) void hloss_part(
    const float* __restrict__ outputs,
    const int*   __restrict__ target,
    float* __restrict__ partials)
{
    __shared__ float red[4];
    const int lane = threadIdx.x & 63;
    const int wid  = threadIdx.x >> 6;
    const int rowbase = blockIdx.x * 16 + wid * 4;   // 4 contiguous rows/wave

    // fetch the wave's 4 targets (lanes 0-3), broadcast via shfl
    int tmine = 0;
    if (lane < 4) tmine = target[rowbase + lane];
    const int t0 = __shfl(tmine, 0, 64);
    const int t1 = __shfl(tmine, 1, 64);
    const int t2 = __shfl(tmine, 2, 64);
    const int t3 = __shfl(tmine, 3, 64);
    const int a0 = (t0 / 100) * 100, b0 = (t0 / 10) * 10;
    const int a1 = (t1 / 100) * 100, b1 = (t1 / 10) * 10;
    const int a2 = (t2 / 100) * 100, b2 = (t2 / 10) * 10;
    const int a3 = (t3 / 100) * 100, b3 = (t3 / 10) * 10;

    // wave's flat region: 4 rows * 250 float4 = 1000 chunks, 128 B aligned
    const float4* f4 = reinterpret_cast<const float4*>(
        outputs + (size_t)rowbase * NCLS);
    const float4 zero4 = {0.f, 0.f, 0.f, 0.f};
    float s0 = 0.f, s1 = 0.f, s2 = 0.f, s3 = 0.f;

    // dynamic loop, 4 independent aligned streams at 0/256/512/768
    for (int c = lane; c < 256; c += 64) {
        const int c1 = c + 256, c2 = c + 512, c3 = c + 768;
        const float4 v0 = f4[c];
        const float4 v1 = f4[c1];
        const float4 v2 = f4[c2];
        const float4 v3 = (c3 < 1000) ? f4[c3] : zero4;   // only tail predicate
        s0 += wchunk(v0, c,  t0,t1,t2,t3, a0,a1,a2,a3, b0,b1,b2,b3);
        s1 += wchunk(v1, c1, t0,t1,t2,t3, a0,a1,a2,a3, b0,b1,b2,b3);
        s2 += wchunk(v2, c2, t0,t1,t2,t3, a0,a1,a2,a3, b0,b1,b2,b3);
        s3 += wchunk(v3, c3, t0,t1,t2,t3, a0,a1,a2,a3, b0,b1,b2,b3); // v3=0 on tail
    }
    float win = (s0 + s1) + (s2 + s3);

    // block reduction: butterfly -> LDS -> one plain store per block
    #pragma unroll
    for (int off = 32; off > 0; off >>= 1)
        win += __shfl_xor(win, off, 64);
    if (lane == 0) red[wid] = win;
    __syncthreads();
    if (threadIdx.x == 0)
        partials[blockIdx.x] = (red[0] + red[1]) + (red[2] + red[3]);
}

// single 64-lane wave: 2048 partials = 8 float4 per lane, butterfly, store.
__global__ __launch_bounds__(64) void hloss_final(
    const float* __restrict__ partials,
    float* __restrict__ out)
{
    const int lane = threadIdx.x;
    const float4* p4 = reinterpret_cast<const float4*>(partials);
    float s = 0.0f;
    #pragma unroll
    for (int k = 0; k < 8; ++k) {              // fixed order: lane + 64*k
        const float4 v = p4[lane + 64 * k];
        s += (v.x + v.y) + (v.z + v.w);
    }
    #pragma unroll
    for (int off = 32; off > 0; off >>= 1)
        s += __shfl_xor(s, off, 64);
    if (lane == 0)
        out[0] = (float)BATCH - s;
}

extern "C" void kernel_launch(void* const* d_in, const int* in_sizes, int n_in,
                              void* d_out, int out_size, void* d_ws, size_t ws_size,
                              hipStream_t stream) {
    const float* outputs = (const float*)d_in[0];
    const int*   target  = (const int*)d_in[1];
    // d_in[2]=A, d_in[3]=W — hierarchy folded analytically (see header).
    float* out      = (float*)d_out;
    float* partials = (float*)d_ws;   // 2048 floats, fully rewritten each call

    hloss_part <<<dim3(BLOCKS), dim3(THREADS), 0, stream>>>(outputs, target, partials);
    hloss_final<<<dim3(1),      dim3(64),      0, stream>>>(partials, out);
}